// Round 1
// baseline (700.864 us; speedup 1.0000x reference)
//
#include <hip/hip_runtime.h>

typedef unsigned short u16;
typedef __attribute__((ext_vector_type(4))) float f32x4;
typedef __attribute__((ext_vector_type(8))) __bf16 bf16x8;
typedef __attribute__((ext_vector_type(8))) u16 u16x8;
typedef __attribute__((ext_vector_type(4))) u16 u16x4;

#define S_LEN 2048
#define HID 2048
#define NH 16
#define NKV 8
#define HD 128
#define SCALE_QK 11.313708498984761f  /* sqrt(128) */

__device__ __forceinline__ float b2f(u16 u) {
    return __uint_as_float(((unsigned int)u) << 16);
}
__device__ __forceinline__ u16 f2b(float f) {
    unsigned int x = __float_as_uint(f);
    unsigned int r = (x + 0x7FFFu + ((x >> 16) & 1u)) >> 16;
    return (u16)r;
}

// ---------------------------------------------------------------- casts
__global__ __launch_bounds__(256) void cast_f32_bf16(const float* __restrict__ src,
                                                     u16* __restrict__ dst, int n4) {
    int i = blockIdx.x * 256 + threadIdx.x;
    if (i < n4) {
        f32x4 v = reinterpret_cast<const f32x4*>(src)[i];
        u16x4 o;
        o[0] = f2b(v[0]); o[1] = f2b(v[1]); o[2] = f2b(v[2]); o[3] = f2b(v[3]);
        reinterpret_cast<u16x4*>(dst)[i] = o;
    }
}

// V slice of QKVf -> vb [g][s][d] bf16
__global__ __launch_bounds__(256) void cast_v(const float* __restrict__ qkvf,
                                              u16* __restrict__ vb) {
    int idx = blockIdx.x * 256 + threadIdx.x;      // 2M threads
    int d = idx & 127;
    int s = (idx >> 7) & 2047;
    int g = idx >> 18;
    vb[idx] = f2b(qkvf[(size_t)s * 4096 + 3072 + g * 128 + d]);
}

// ---------------------------------------------------------------- GEMM  C[M][N] = A[M][K] * B[N][K]^T   (bf16 in, f32 out)
#define BM 128
#define BN 128
#define BK 32
#define LDSK 40

__global__ __launch_bounds__(256) void gemm_bt(const u16* __restrict__ A,
                                               const u16* __restrict__ B,
                                               float* __restrict__ C,
                                               int M, int N, int K) {
    __shared__ u16 As[BM * LDSK];
    __shared__ u16 Bs[BN * LDSK];
    int tid = threadIdx.x;
    int lane = tid & 63, wave = tid >> 6;
    int row0 = blockIdx.y * BM, col0 = blockIdx.x * BN;
    int wr = (wave >> 1) * 64, wc = (wave & 1) * 64;

    f32x4 acc[4][4] = {};

    int sr = tid >> 2;             // 0..63
    int sc = (tid & 3) * 8;        // 0,8,16,24

    for (int k0 = 0; k0 < K; k0 += BK) {
        // stage A,B tiles (each thread: 2 chunks of 8 bf16 per tile)
        *reinterpret_cast<u16x8*>(&As[sr * LDSK + sc]) =
            *reinterpret_cast<const u16x8*>(A + (size_t)(row0 + sr) * K + k0 + sc);
        *reinterpret_cast<u16x8*>(&As[(sr + 64) * LDSK + sc]) =
            *reinterpret_cast<const u16x8*>(A + (size_t)(row0 + sr + 64) * K + k0 + sc);
        *reinterpret_cast<u16x8*>(&Bs[sr * LDSK + sc]) =
            *reinterpret_cast<const u16x8*>(B + (size_t)(col0 + sr) * K + k0 + sc);
        *reinterpret_cast<u16x8*>(&Bs[(sr + 64) * LDSK + sc]) =
            *reinterpret_cast<const u16x8*>(B + (size_t)(col0 + sr + 64) * K + k0 + sc);
        __syncthreads();

        int l15 = lane & 15, kg = (lane >> 4) * 8;
        bf16x8 af[4], bg[4];
#pragma unroll
        for (int m = 0; m < 4; m++)
            af[m] = *reinterpret_cast<const bf16x8*>(&As[(wr + m * 16 + l15) * LDSK + kg]);
#pragma unroll
        for (int n = 0; n < 4; n++)
            bg[n] = *reinterpret_cast<const bf16x8*>(&Bs[(wc + n * 16 + l15) * LDSK + kg]);
#pragma unroll
        for (int m = 0; m < 4; m++)
#pragma unroll
            for (int n = 0; n < 4; n++)
                acc[m][n] = __builtin_amdgcn_mfma_f32_16x16x32_bf16(af[m], bg[n], acc[m][n], 0, 0, 0);
        __syncthreads();
    }

    int l15 = lane & 15, l4 = lane >> 4;
#pragma unroll
    for (int m = 0; m < 4; m++)
#pragma unroll
        for (int n = 0; n < 4; n++)
#pragma unroll
            for (int r = 0; r < 4; r++) {
                int row = row0 + wr + m * 16 + l4 * 4 + r;
                int col = col0 + wc + n * 16 + l15;
                C[(size_t)row * N + col] = acc[m][n][r];
            }
}

// ---------------------------------------------------------------- RoPE + L2 norm
// one wave per (s,h) row
__global__ __launch_bounds__(256) void rope_norm_q(const float* __restrict__ qkvf,
                                                   const float* __restrict__ cosb,
                                                   const float* __restrict__ sinb,
                                                   const float* __restrict__ sqkw,
                                                   u16* __restrict__ qb) {
    int w = blockIdx.x * 4 + (threadIdx.x >> 6);
    int lane = threadIdx.x & 63;
    int h = w & (NH - 1), s = w >> 4;
    const float* src = qkvf + (size_t)s * 4096 + h * 128;
    float x0 = src[lane], x1 = src[lane + 64];
    float c0 = cosb[s * 128 + lane], c1 = cosb[s * 128 + 64 + lane];
    float s0 = sinb[s * 128 + lane], s1 = sinb[s * 128 + 64 + lane];
    float y0 = x0 * c0 - x1 * s0;
    float y1 = x1 * c1 + x0 * s1;
    float ss = y0 * y0 + y1 * y1;
#pragma unroll
    for (int off = 32; off; off >>= 1) ss += __shfl_xor(ss, off);
    float inv = 1.f / (sqrtf(ss) + 1e-8f);
    float w0 = sqkw[h * 128 + lane] * 50.f;
    float w1 = sqkw[h * 128 + 64 + lane] * 50.f;
    y0 *= inv * w0 * w0;
    y1 *= inv * w1 * w1;
    u16* dst = qb + ((size_t)h * S_LEN + s) * 128;
    dst[lane] = f2b(y0);
    dst[lane + 64] = f2b(y1);
}

__global__ __launch_bounds__(256) void rope_norm_k(const float* __restrict__ qkvf,
                                                   const float* __restrict__ cosb,
                                                   const float* __restrict__ sinb,
                                                   u16* __restrict__ kb) {
    int w = blockIdx.x * 4 + (threadIdx.x >> 6);
    int lane = threadIdx.x & 63;
    int g = w & (NKV - 1), s = w >> 3;
    const float* src = qkvf + (size_t)s * 4096 + 2048 + g * 128;
    float x0 = src[lane], x1 = src[lane + 64];
    float c0 = cosb[s * 128 + lane], c1 = cosb[s * 128 + 64 + lane];
    float s0 = sinb[s * 128 + lane], s1 = sinb[s * 128 + 64 + lane];
    float y0 = x0 * c0 - x1 * s0;
    float y1 = x1 * c1 + x0 * s1;
    float ss = y0 * y0 + y1 * y1;
#pragma unroll
    for (int off = 32; off; off >>= 1) ss += __shfl_xor(ss, off);
    float inv = 1.f / (sqrtf(ss) + 1e-8f);
    u16* dst = kb + ((size_t)g * S_LEN + s) * 128;
    dst[lane] = f2b(y0 * inv);
    dst[lane + 64] = f2b(y1 * inv);
}

// ---------------------------------------------------------------- attention
// block: 8 q rows of one head; 4 waves, wave wv owns rows 2wv, 2wv+1.
// K/V tiles of 64 keys staged in LDS. Online softmax. Causal.
#define KTILE 64
#define KPAD 132

__global__ __launch_bounds__(256) void attn_kernel(const u16* __restrict__ Qb,  // [16][S][128]
                                                   const u16* __restrict__ Kb,  // [8][S][128]
                                                   const u16* __restrict__ Vb,  // [8][S][128]
                                                   u16* __restrict__ Ao) {      // [S][2048]
    __shared__ float qs[8][128];
    __shared__ u16 Ks[KTILE][KPAD];
    __shared__ u16 Vs[KTILE][KPAD];
    __shared__ float psT[KTILE][8];

    int tid = threadIdx.x, lane = tid & 63, wv = tid >> 6;
    int h = blockIdx.x & (NH - 1);
    int qb0 = (blockIdx.x >> 4) * 8;
    int g = h >> 1;

    for (int i = tid; i < 8 * 128; i += 256) {
        int r = i >> 7, d = i & 127;
        qs[r][d] = b2f(Qb[((size_t)h * S_LEN + qb0 + r) * 128 + d]);
    }

    int rA = wv * 2, rB = wv * 2 + 1;
    int qrA = qb0 + rA, qrB = qb0 + rB;
    float mA = -1e30f, mB = -1e30f, lA = 0.f, lB = 0.f;
    float accA0 = 0.f, accA1 = 0.f, accB0 = 0.f, accB1 = 0.f;
    int d0 = lane * 2;
    int nt = (qb0 + 8 + 63) >> 6;

    for (int t = 0; t < nt; ++t) {
        int k0 = t * KTILE;
        __syncthreads();  // previous tile fully consumed (also covers qs on t=0)
        for (int ci = tid; ci < KTILE * 32; ci += 256) {
            int r = ci >> 5, c = (ci & 31) * 4;
            *reinterpret_cast<u16x4*>(&Ks[r][c]) =
                *reinterpret_cast<const u16x4*>(&Kb[((size_t)g * S_LEN + k0 + r) * 128 + c]);
            *reinterpret_cast<u16x4*>(&Vs[r][c]) =
                *reinterpret_cast<const u16x4*>(&Vb[((size_t)g * S_LEN + k0 + r) * 128 + c]);
        }
        __syncthreads();

        int key = k0 + lane;
        float sA = 0.f, sB = 0.f;
#pragma unroll 8
        for (int d = 0; d < 128; d += 4) {
            u16x4 kv4 = *reinterpret_cast<const u16x4*>(&Ks[lane][d]);
            f32x4 qa = *reinterpret_cast<const f32x4*>(&qs[rA][d]);
            f32x4 qc = *reinterpret_cast<const f32x4*>(&qs[rB][d]);
#pragma unroll
            for (int j = 0; j < 4; j++) {
                float kf = b2f(kv4[j]);
                sA += qa[j] * kf;
                sB += qc[j] * kf;
            }
        }
        sA *= SCALE_QK; sB *= SCALE_QK;
        if (key > qrA) sA = -1e30f;
        if (key > qrB) sB = -1e30f;

        float tmA = sA, tmB = sB;
#pragma unroll
        for (int off = 32; off; off >>= 1) {
            tmA = fmaxf(tmA, __shfl_xor(tmA, off));
            tmB = fmaxf(tmB, __shfl_xor(tmB, off));
        }
        float nmA = fmaxf(mA, tmA), nmB = fmaxf(mB, tmB);
        float scA = __expf(mA - nmA), scB = __expf(mB - nmB);
        float pA = __expf(sA - nmA), pB = __expf(sB - nmB);
        float sumA = pA, sumB = pB;
#pragma unroll
        for (int off = 32; off; off >>= 1) {
            sumA += __shfl_xor(sumA, off);
            sumB += __shfl_xor(sumB, off);
        }
        lA = lA * scA + sumA; lB = lB * scB + sumB;
        mA = nmA; mB = nmB;
        accA0 *= scA; accA1 *= scA; accB0 *= scB; accB1 *= scB;
        psT[lane][rA] = pA;
        psT[lane][rB] = pB;   // wave-private columns; no barrier needed

#pragma unroll 4
        for (int j = 0; j < KTILE; ++j) {
            float2 p2 = *reinterpret_cast<const float2*>(&psT[j][rA]);
            unsigned int v2 = *reinterpret_cast<const unsigned int*>(&Vs[j][d0]);
            float v0 = b2f((u16)(v2 & 0xffffu));
            float v1 = b2f((u16)(v2 >> 16));
            accA0 += p2.x * v0; accA1 += p2.x * v1;
            accB0 += p2.y * v0; accB1 += p2.y * v1;
        }
    }

    float invA = 1.f / lA, invB = 1.f / lB;
    unsigned int packA = (unsigned int)f2b(accA0 * invA) | ((unsigned int)f2b(accA1 * invA) << 16);
    unsigned int packB = (unsigned int)f2b(accB0 * invB) | ((unsigned int)f2b(accB1 * invB) << 16);
    *reinterpret_cast<unsigned int*>(&Ao[(size_t)qrA * 2048 + h * 128 + d0]) = packA;
    *reinterpret_cast<unsigned int*>(&Ao[(size_t)qrB * 2048 + h * 128 + d0]) = packB;
}

// ---------------------------------------------------------------- launch
extern "C" void kernel_launch(void* const* d_in, const int* in_sizes, int n_in,
                              void* d_out, int out_size, void* d_ws, size_t ws_size,
                              hipStream_t stream) {
    const float* hs   = (const float*)d_in[0];
    const float* cosb = (const float*)d_in[1];
    const float* sinb = (const float*)d_in[2];
    // d_in[3] attention_mask: pure causal, implemented analytically
    const float* Wq   = (const float*)d_in[4];
    const float* Wk   = (const float*)d_in[5];
    const float* Wv   = (const float*)d_in[6];
    const float* Wo   = (const float*)d_in[7];
    const float* sqkw = (const float*)d_in[8];

    char* ws = (char*)d_ws;
    u16*   hsb  = (u16*)(ws);                       //  8.4 MB  [2048][2048] bf16
    u16*   wcat = (u16*)(ws + 8388608);             // 16.8 MB  [4096][2048] bf16 (Wq;Wk;Wv)
    u16*   wob  = (u16*)(ws + 25165824);            //  8.4 MB  [2048][2048] bf16
    float* qkvf = (float*)(ws + 33554432);          // 33.6 MB  [2048][4096] f32
    u16*   qb   = (u16*)(ws + 67108864);            //  8.4 MB  [16][2048][128] bf16
    u16*   kb   = (u16*)(ws + 75497472);            //  4.2 MB  [8][2048][128] bf16
    u16*   vb   = (u16*)(ws + 79691776);            //  4.2 MB  [8][2048][128] bf16
    u16*   ao   = (u16*)(ws + 83886080);            //  8.4 MB  [2048][2048] bf16
    // total ws: 92.3 MB

    // casts
    cast_f32_bf16<<<4096, 256, 0, stream>>>(hs, hsb, 1048576);
    cast_f32_bf16<<<4096, 256, 0, stream>>>(Wq, wcat, 1048576);
    cast_f32_bf16<<<2048, 256, 0, stream>>>(Wk, wcat + 4194304, 524288);
    cast_f32_bf16<<<2048, 256, 0, stream>>>(Wv, wcat + 6291456, 524288);
    cast_f32_bf16<<<4096, 256, 0, stream>>>(Wo, wob, 1048576);

    // QKV projection: [2048][4096] = hsb * wcat^T
    gemm_bt<<<dim3(32, 16), 256, 0, stream>>>(hsb, wcat, qkvf, 2048, 4096, 2048);

    // RoPE + norms + V cast
    rope_norm_q<<<8192, 256, 0, stream>>>(qkvf, cosb, sinb, sqkw, qb);
    rope_norm_k<<<4096, 256, 0, stream>>>(qkvf, cosb, sinb, kb);
    cast_v<<<8192, 256, 0, stream>>>(qkvf, vb);

    // attention
    attn_kernel<<<4096, 256, 0, stream>>>(qb, kb, vb, ao);

    // output projection -> f32 d_out
    gemm_bt<<<dim3(16, 16), 256, 0, stream>>>(ao, wob, (float*)d_out, 2048, 2048, 2048);
}

// Round 2
// 276.508 us; speedup vs baseline: 2.5347x; 2.5347x over previous
//
#include <hip/hip_runtime.h>

typedef unsigned short u16;
typedef __attribute__((ext_vector_type(4))) float f32x4;
typedef __attribute__((ext_vector_type(8))) __bf16 bf16x8;
typedef __attribute__((ext_vector_type(8))) u16 u16x8;
typedef __attribute__((ext_vector_type(4))) u16 u16x4;

#define S_LEN 2048
#define HID 2048
#define NH 16
#define NKV 8
#define HD 128
#define SCALE_QK 11.313708498984761f  /* sqrt(128) */

__device__ __forceinline__ float b2f(u16 u) {
    return __uint_as_float(((unsigned int)u) << 16);
}
__device__ __forceinline__ u16 f2b(float f) {
    unsigned int x = __float_as_uint(f);
    unsigned int r = (x + 0x7FFFu + ((x >> 16) & 1u)) >> 16;
    return (u16)r;
}

// ---------------------------------------------------------------- casts
__global__ __launch_bounds__(256) void cast_f32_bf16(const float* __restrict__ src,
                                                     u16* __restrict__ dst, int n4) {
    int i = blockIdx.x * 256 + threadIdx.x;
    if (i < n4) {
        f32x4 v = reinterpret_cast<const f32x4*>(src)[i];
        u16x4 o;
        o[0] = f2b(v[0]); o[1] = f2b(v[1]); o[2] = f2b(v[2]); o[3] = f2b(v[3]);
        reinterpret_cast<u16x4*>(dst)[i] = o;
    }
}

// V slice of QKVf -> vt [gd=g*128+d][s] bf16 (transposed for PV B-frags)
__global__ __launch_bounds__(256) void cast_v_t(const float* __restrict__ qkvf,
                                                u16* __restrict__ vt) {
    __shared__ float tile[64][65];
    int s0 = (blockIdx.x & 31) * 64;       // 32 s-tiles
    int c0 = (blockIdx.x >> 5) * 64;       // 16 d-col tiles (1024 total V cols)
    for (int i = threadIdx.x; i < 64 * 64; i += 256) {
        int r = i >> 6, c = i & 63;
        tile[r][c] = qkvf[(size_t)(s0 + r) * 4096 + 3072 + c0 + c];
    }
    __syncthreads();
    for (int i = threadIdx.x; i < 64 * 64; i += 256) {
        int r = i >> 6, c = i & 63;        // r = d-local, c = s-local
        vt[(size_t)(c0 + r) * 2048 + s0 + c] = f2b(tile[c][r]);
    }
}

// ---------------------------------------------------------------- GEMM  C[M][N] = A[M][K] * B[N][K]^T   (bf16 in, f32 out)
#define BM 128
#define BN 128
#define BK 32
#define LDSK 40

__global__ __launch_bounds__(256) void gemm_bt(const u16* __restrict__ A,
                                               const u16* __restrict__ B,
                                               float* __restrict__ C,
                                               int M, int N, int K) {
    __shared__ u16 As[BM * LDSK];
    __shared__ u16 Bs[BN * LDSK];
    int tid = threadIdx.x;
    int lane = tid & 63, wave = tid >> 6;
    int row0 = blockIdx.y * BM, col0 = blockIdx.x * BN;
    int wr = (wave >> 1) * 64, wc = (wave & 1) * 64;

    f32x4 acc[4][4] = {};

    int sr = tid >> 2;             // 0..63
    int sc = (tid & 3) * 8;        // 0,8,16,24

    for (int k0 = 0; k0 < K; k0 += BK) {
        *reinterpret_cast<u16x8*>(&As[sr * LDSK + sc]) =
            *reinterpret_cast<const u16x8*>(A + (size_t)(row0 + sr) * K + k0 + sc);
        *reinterpret_cast<u16x8*>(&As[(sr + 64) * LDSK + sc]) =
            *reinterpret_cast<const u16x8*>(A + (size_t)(row0 + sr + 64) * K + k0 + sc);
        *reinterpret_cast<u16x8*>(&Bs[sr * LDSK + sc]) =
            *reinterpret_cast<const u16x8*>(B + (size_t)(col0 + sr) * K + k0 + sc);
        *reinterpret_cast<u16x8*>(&Bs[(sr + 64) * LDSK + sc]) =
            *reinterpret_cast<const u16x8*>(B + (size_t)(col0 + sr + 64) * K + k0 + sc);
        __syncthreads();

        int l15 = lane & 15, kg = (lane >> 4) * 8;
        bf16x8 af[4], bg[4];
#pragma unroll
        for (int m = 0; m < 4; m++)
            af[m] = *reinterpret_cast<const bf16x8*>(&As[(wr + m * 16 + l15) * LDSK + kg]);
#pragma unroll
        for (int n = 0; n < 4; n++)
            bg[n] = *reinterpret_cast<const bf16x8*>(&Bs[(wc + n * 16 + l15) * LDSK + kg]);
#pragma unroll
        for (int m = 0; m < 4; m++)
#pragma unroll
            for (int n = 0; n < 4; n++)
                acc[m][n] = __builtin_amdgcn_mfma_f32_16x16x32_bf16(af[m], bg[n], acc[m][n], 0, 0, 0);
        __syncthreads();
    }

    int l15 = lane & 15, l4 = lane >> 4;
#pragma unroll
    for (int m = 0; m < 4; m++)
#pragma unroll
        for (int n = 0; n < 4; n++)
#pragma unroll
            for (int r = 0; r < 4; r++) {
                int row = row0 + wr + m * 16 + l4 * 4 + r;
                int col = col0 + wc + n * 16 + l15;
                C[(size_t)row * N + col] = acc[m][n][r];
            }
}

// ---------------------------------------------------------------- RoPE + L2 norm
__global__ __launch_bounds__(256) void rope_norm_q(const float* __restrict__ qkvf,
                                                   const float* __restrict__ cosb,
                                                   const float* __restrict__ sinb,
                                                   const float* __restrict__ sqkw,
                                                   u16* __restrict__ qb) {
    int w = blockIdx.x * 4 + (threadIdx.x >> 6);
    int lane = threadIdx.x & 63;
    int h = w & (NH - 1), s = w >> 4;
    const float* src = qkvf + (size_t)s * 4096 + h * 128;
    float x0 = src[lane], x1 = src[lane + 64];
    float c0 = cosb[s * 128 + lane], c1 = cosb[s * 128 + 64 + lane];
    float s0 = sinb[s * 128 + lane], s1 = sinb[s * 128 + 64 + lane];
    float y0 = x0 * c0 - x1 * s0;
    float y1 = x1 * c1 + x0 * s1;
    float ss = y0 * y0 + y1 * y1;
#pragma unroll
    for (int off = 32; off; off >>= 1) ss += __shfl_xor(ss, off);
    float inv = 1.f / (sqrtf(ss) + 1e-8f);
    float w0 = sqkw[h * 128 + lane] * 50.f;
    float w1 = sqkw[h * 128 + 64 + lane] * 50.f;
    y0 *= inv * w0 * w0;
    y1 *= inv * w1 * w1;
    u16* dst = qb + ((size_t)h * S_LEN + s) * 128;
    dst[lane] = f2b(y0);
    dst[lane + 64] = f2b(y1);
}

__global__ __launch_bounds__(256) void rope_norm_k(const float* __restrict__ qkvf,
                                                   const float* __restrict__ cosb,
                                                   const float* __restrict__ sinb,
                                                   u16* __restrict__ kb) {
    int w = blockIdx.x * 4 + (threadIdx.x >> 6);
    int lane = threadIdx.x & 63;
    int g = w & (NKV - 1), s = w >> 3;
    const float* src = qkvf + (size_t)s * 4096 + 2048 + g * 128;
    float x0 = src[lane], x1 = src[lane + 64];
    float c0 = cosb[s * 128 + lane], c1 = cosb[s * 128 + 64 + lane];
    float s0 = sinb[s * 128 + lane], s1 = sinb[s * 128 + 64 + lane];
    float y0 = x0 * c0 - x1 * s0;
    float y1 = x1 * c1 + x0 * s1;
    float ss = y0 * y0 + y1 * y1;
#pragma unroll
    for (int off = 32; off; off >>= 1) ss += __shfl_xor(ss, off);
    float inv = 1.f / (sqrtf(ss) + 1e-8f);
    u16* dst = kb + ((size_t)g * S_LEN + s) * 128;
    dst[lane] = f2b(y0 * inv);
    dst[lane + 64] = f2b(y1 * inv);
}

// ---------------------------------------------------------------- MFMA flash attention
// Block: 64 q-rows of one head, 4 waves x 16 q-rows. K-tiles of 64 keys.
// Qs/Ks: [64 rows][128 d] bf16, XOR-swizzled (byte ^= (row&7)<<4).
// Vs: [128 d][64 keys] bf16 (from pre-transposed vt), XOR-swizzled.
// P goes through wave-private padded LDS to re-layout for the PV A-frag.
__global__ __launch_bounds__(256) void attn_mfma(const u16* __restrict__ Qb,  // [16][S][128]
                                                 const u16* __restrict__ Kb,  // [8][S][128]
                                                 const u16* __restrict__ Vt,  // [1024][S]
                                                 u16* __restrict__ Ao) {      // [S][2048]
    __shared__ alignas(16) u16 Qs[64 * 128];
    __shared__ alignas(16) u16 Ks[64 * 128];
    __shared__ alignas(16) u16 Vs[128 * 64];
    __shared__ alignas(16) u16 Pb[4][16][72];

    int tid = threadIdx.x, lane = tid & 63, wv = tid >> 6;
    int h = blockIdx.x & (NH - 1);
    int qi = 31 - (blockIdx.x >> 4);       // big-work blocks first
    int qb0 = qi * 64;
    int g = h >> 1;
    int l15 = lane & 15, lg = lane >> 4;

    // stage Q (swizzled)
    for (int i = tid; i < 64 * 16; i += 256) {
        int r = i >> 4, c = i & 15;
        u16x8 v = *reinterpret_cast<const u16x8*>(&Qb[((size_t)h * S_LEN + qb0 + r) * 128 + c * 8]);
        *reinterpret_cast<u16x8*>((char*)Qs + r * 256 + ((c * 16) ^ ((r & 7) << 4))) = v;
    }
    __syncthreads();

    // wave's Q fragments, held in registers for the whole kernel
    bf16x8 qf[4];
    {
        int r = wv * 16 + l15;
#pragma unroll
        for (int kd = 0; kd < 4; kd++) {
            int col = kd * 64 + lg * 16;
            qf[kd] = *reinterpret_cast<const bf16x8*>((char*)Qs + r * 256 + (col ^ ((r & 7) << 4)));
        }
    }

    float m[4], l[4];
    f32x4 oacc[8];
#pragma unroll
    for (int r = 0; r < 4; r++) { m[r] = -1e30f; l[r] = 0.f; }
#pragma unroll
    for (int dt = 0; dt < 8; dt++) oacc[dt] = (f32x4){0.f, 0.f, 0.f, 0.f};

    int nt = qi + 1;
    for (int t = 0; t < nt; ++t) {
        int k0 = t * 64;
        __syncthreads();   // previous tile fully consumed
        // stage K tile [64 keys][128 d], swizzled
        for (int i = tid; i < 64 * 16; i += 256) {
            int r = i >> 4, c = i & 15;
            u16x8 v = *reinterpret_cast<const u16x8*>(&Kb[((size_t)g * S_LEN + k0 + r) * 128 + c * 8]);
            *reinterpret_cast<u16x8*>((char*)Ks + r * 256 + ((c * 16) ^ ((r & 7) << 4))) = v;
        }
        // stage V tile [128 d][64 keys] from transposed vt, swizzled
        for (int i = tid; i < 128 * 8; i += 256) {
            int r = i >> 3, c = i & 7;
            u16x8 v = *reinterpret_cast<const u16x8*>(&Vt[((size_t)g * 128 + r) * S_LEN + k0 + c * 8]);
            *reinterpret_cast<u16x8*>((char*)Vs + r * 128 + ((c * 16) ^ ((r & 7) << 4))) = v;
        }
        __syncthreads();

        // S = Q K^T  (4 key sub-tiles of 16, K-dim 128 = 4x32)
        f32x4 sacc[4];
#pragma unroll
        for (int kt = 0; kt < 4; kt++) sacc[kt] = (f32x4){0.f, 0.f, 0.f, 0.f};
#pragma unroll
        for (int kt = 0; kt < 4; kt++) {
            int r = kt * 16 + l15;
#pragma unroll
            for (int kd = 0; kd < 4; kd++) {
                int col = kd * 64 + lg * 16;
                bf16x8 kf = *reinterpret_cast<const bf16x8*>((char*)Ks + r * 256 + (col ^ ((r & 7) << 4)));
                sacc[kt] = __builtin_amdgcn_mfma_f32_16x16x32_bf16(qf[kd], kf, sacc[kt], 0, 0, 0);
            }
        }

        // scale + causal mask (only the diagonal tile needs masking: k0 == qb0 there)
        bool maskt = (t == nt - 1);
#pragma unroll
        for (int kt = 0; kt < 4; kt++)
#pragma unroll
            for (int r = 0; r < 4; r++) {
                float s = sacc[kt][r] * SCALE_QK;
                if (maskt) {
                    int key = k0 + kt * 16 + l15;
                    int q = qb0 + wv * 16 + lg * 4 + r;
                    if (key > q) s = -1e30f;
                }
                sacc[kt][r] = s;
            }

        // online softmax: rows live across 16-lane groups (reduce via shfl_xor 1/2/4/8)
        float pnew[4][4];  // [kt][reg]
        float scl[4];
#pragma unroll
        for (int r = 0; r < 4; r++) {
            float tm = fmaxf(fmaxf(sacc[0][r], sacc[1][r]), fmaxf(sacc[2][r], sacc[3][r]));
            tm = fmaxf(tm, __shfl_xor(tm, 1));
            tm = fmaxf(tm, __shfl_xor(tm, 2));
            tm = fmaxf(tm, __shfl_xor(tm, 4));
            tm = fmaxf(tm, __shfl_xor(tm, 8));
            float mn = fmaxf(m[r], tm);
            scl[r] = __expf(m[r] - mn);
            m[r] = mn;
            float ls = 0.f;
#pragma unroll
            for (int kt = 0; kt < 4; kt++) {
                float p = __expf(sacc[kt][r] - mn);
                pnew[kt][r] = p;
                ls += p;
            }
            ls += __shfl_xor(ls, 1);
            ls += __shfl_xor(ls, 2);
            ls += __shfl_xor(ls, 4);
            ls += __shfl_xor(ls, 8);
            l[r] = l[r] * scl[r] + ls;
        }

        // rescale O accumulator
#pragma unroll
        for (int dt = 0; dt < 8; dt++)
#pragma unroll
            for (int r = 0; r < 4; r++) oacc[dt][r] *= scl[r];

        // P -> wave-private LDS (bf16), re-layout for PV A-frags
#pragma unroll
        for (int kt = 0; kt < 4; kt++)
#pragma unroll
            for (int r = 0; r < 4; r++)
                Pb[wv][lg * 4 + r][kt * 16 + l15] = f2b(pnew[kt][r]);

        // O += P V   (2 key-slices of 32, 8 d-tiles of 16)
#pragma unroll
        for (int ks = 0; ks < 2; ks++) {
            bf16x8 pf = *reinterpret_cast<const bf16x8*>(&Pb[wv][l15][ks * 32 + lg * 8]);
#pragma unroll
            for (int dt = 0; dt < 8; dt++) {
                int r = dt * 16 + l15;
                int col = ks * 64 + lg * 16;
                bf16x8 vf = *reinterpret_cast<const bf16x8*>((char*)Vs + r * 128 + (col ^ ((r & 7) << 4)));
                oacc[dt] = __builtin_amdgcn_mfma_f32_16x16x32_bf16(pf, vf, oacc[dt], 0, 0, 0);
            }
        }
    }

    // epilogue: normalize and store
    float inv[4];
#pragma unroll
    for (int r = 0; r < 4; r++) inv[r] = 1.f / l[r];
#pragma unroll
    for (int dt = 0; dt < 8; dt++)
#pragma unroll
        for (int r = 0; r < 4; r++) {
            int q = qb0 + wv * 16 + lg * 4 + r;
            Ao[(size_t)q * 2048 + h * 128 + dt * 16 + l15] = f2b(oacc[dt][r] * inv[r]);
        }
}

// ---------------------------------------------------------------- launch
extern "C" void kernel_launch(void* const* d_in, const int* in_sizes, int n_in,
                              void* d_out, int out_size, void* d_ws, size_t ws_size,
                              hipStream_t stream) {
    const float* hs   = (const float*)d_in[0];
    const float* cosb = (const float*)d_in[1];
    const float* sinb = (const float*)d_in[2];
    // d_in[3] attention_mask: pure causal, implemented analytically
    const float* Wq   = (const float*)d_in[4];
    const float* Wk   = (const float*)d_in[5];
    const float* Wv   = (const float*)d_in[6];
    const float* Wo   = (const float*)d_in[7];
    const float* sqkw = (const float*)d_in[8];

    char* ws = (char*)d_ws;
    u16*   hsb  = (u16*)(ws);                       //  8.4 MB  [2048][2048] bf16
    u16*   wcat = (u16*)(ws + 8388608);             // 16.8 MB  [4096][2048] bf16 (Wq;Wk;Wv)
    u16*   wob  = (u16*)(ws + 25165824);            //  8.4 MB  [2048][2048] bf16
    float* qkvf = (float*)(ws + 33554432);          // 33.6 MB  [2048][4096] f32
    u16*   qb   = (u16*)(ws + 67108864);            //  8.4 MB  [16][2048][128] bf16
    u16*   kb   = (u16*)(ws + 75497472);            //  4.2 MB  [8][2048][128] bf16
    u16*   vt   = (u16*)(ws + 79691776);            //  4.2 MB  [1024][2048] bf16 (V^T)
    u16*   ao   = (u16*)(ws + 83886080);            //  8.4 MB  [2048][2048] bf16

    // casts
    cast_f32_bf16<<<4096, 256, 0, stream>>>(hs, hsb, 1048576);
    cast_f32_bf16<<<4096, 256, 0, stream>>>(Wq, wcat, 1048576);
    cast_f32_bf16<<<2048, 256, 0, stream>>>(Wk, wcat + 4194304, 524288);
    cast_f32_bf16<<<2048, 256, 0, stream>>>(Wv, wcat + 6291456, 524288);
    cast_f32_bf16<<<4096, 256, 0, stream>>>(Wo, wob, 1048576);

    // QKV projection: [2048][4096] = hsb * wcat^T
    gemm_bt<<<dim3(32, 16), 256, 0, stream>>>(hsb, wcat, qkvf, 2048, 4096, 2048);

    // RoPE + norms + V transpose-cast
    rope_norm_q<<<8192, 256, 0, stream>>>(qkvf, cosb, sinb, sqkw, qb);
    rope_norm_k<<<4096, 256, 0, stream>>>(qkvf, cosb, sinb, kb);
    cast_v_t<<<512, 256, 0, stream>>>(qkvf, vt);

    // MFMA flash attention
    attn_mfma<<<512, 256, 0, stream>>>(qb, kb, vt, ao);

    // output projection -> f32 d_out
    gemm_bt<<<dim3(16, 16), 256, 0, stream>>>(ao, wob, (float*)d_out, 2048, 2048, 2048);
}

// Round 3
// 196.778 us; speedup vs baseline: 3.5617x; 1.4052x over previous
//
#include <hip/hip_runtime.h>

typedef unsigned short u16;
typedef __attribute__((ext_vector_type(4))) float f32x4;
typedef __attribute__((ext_vector_type(8))) __bf16 bf16x8;
typedef __attribute__((ext_vector_type(8))) u16 u16x8;
typedef __attribute__((ext_vector_type(4))) u16 u16x4;

#define S_LEN 2048
#define NH 16
#define NKV 8
#define SCALE_QK 11.313708498984761f  /* sqrt(128) */

#define AS1(p) ((const __attribute__((address_space(1))) void*)(p))
#define AS3(p) ((__attribute__((address_space(3))) void*)(p))

__device__ __forceinline__ float b2f(u16 u) {
    return __uint_as_float(((unsigned int)u) << 16);
}
__device__ __forceinline__ u16 f2b(float f) {
    unsigned int x = __float_as_uint(f);
    unsigned int r = (x + 0x7FFFu + ((x >> 16) & 1u)) >> 16;
    return (u16)r;
}

// ---------------------------------------------------------------- fused casts
// quad index space: hs | Wq | Wk | Wv | Wo
__global__ __launch_bounds__(256) void cast_all(const float* __restrict__ hs,
                                                const float* __restrict__ Wq,
                                                const float* __restrict__ Wk,
                                                const float* __restrict__ Wv,
                                                const float* __restrict__ Wo,
                                                u16* __restrict__ hsb,
                                                u16* __restrict__ wcat,
                                                u16* __restrict__ wob) {
    int i = blockIdx.x * 256 + threadIdx.x;   // 0 .. 4194303 quads
    const float* src; u16* dst; int off;
    if (i < 1048576)      { src = hs; dst = hsb;            off = i; }
    else if (i < 2097152) { src = Wq; dst = wcat;           off = i - 1048576; }
    else if (i < 2621440) { src = Wk; dst = wcat + 4194304; off = i - 2097152; }
    else if (i < 3145728) { src = Wv; dst = wcat + 6291456; off = i - 2621440; }
    else                  { src = Wo; dst = wob;            off = i - 3145728; }
    f32x4 v = reinterpret_cast<const f32x4*>(src)[off];
    u16x4 o;
    o[0] = f2b(v[0]); o[1] = f2b(v[1]); o[2] = f2b(v[2]); o[3] = f2b(v[3]);
    reinterpret_cast<u16x4*>(dst)[off] = o;
}

// V slice of QKVf -> vt [gd=g*128+d][s] bf16 (transposed for PV B-frags)
__global__ __launch_bounds__(256) void cast_v_t(const float* __restrict__ qkvf,
                                                u16* __restrict__ vt) {
    __shared__ float tile[64][65];
    int s0 = (blockIdx.x & 31) * 64;
    int c0 = (blockIdx.x >> 5) * 64;
    for (int i = threadIdx.x; i < 64 * 64; i += 256) {
        int r = i >> 6, c = i & 63;
        tile[r][c] = qkvf[(size_t)(s0 + r) * 4096 + 3072 + c0 + c];
    }
    __syncthreads();
    for (int i = threadIdx.x; i < 64 * 64; i += 256) {
        int r = i >> 6, c = i & 63;
        vt[(size_t)(c0 + r) * 2048 + s0 + c] = f2b(tile[c][r]);
    }
}

// ---------------------------------------------------------------- GEMM (m97 structure)
// C[M][N] = A[M][K] * B[N][K]^T, bf16 in, f32 out. 128x128 tile, BK=64,
// linear LDS + global_load_lds width-16 staging, 2-barrier K-loop.
__global__ __launch_bounds__(256) void gemm2(const u16* __restrict__ A,
                                             const u16* __restrict__ B,
                                             float* __restrict__ C,
                                             int M, int N, int K) {
    __shared__ alignas(16) u16 As[128 * 64];
    __shared__ alignas(16) u16 Bs[128 * 64];
    int tid = threadIdx.x, lane = tid & 63, wave = tid >> 6;
    int row0 = blockIdx.y * 128, col0 = blockIdx.x * 128;
    int wr = (wave >> 1) * 64, wc = (wave & 1) * 64;
    int l15 = lane & 15, lg = lane >> 4;

    f32x4 acc[4][4] = {};

    for (int k0 = 0; k0 < K; k0 += 64) {
        __syncthreads();   // previous tile fully consumed
#pragma unroll
        for (int i = 0; i < 4; i++) {
            int slot = i * 4 + wave;            // 0..15 (wave-uniform)
            int r = slot * 8 + (lane >> 3);     // tile row 0..127
            int c = lane & 7;                   // 16B chunk in row
            __builtin_amdgcn_global_load_lds(AS1(A + (size_t)(row0 + r) * K + k0 + c * 8),
                                             AS3(As + slot * 512), 16, 0, 0);
            __builtin_amdgcn_global_load_lds(AS1(B + (size_t)(col0 + r) * K + k0 + c * 8),
                                             AS3(Bs + slot * 512), 16, 0, 0);
        }
        __syncthreads();   // drains vmcnt -> tiles ready

        __builtin_amdgcn_s_setprio(1);
#pragma unroll
        for (int kk = 0; kk < 2; kk++) {
            bf16x8 af[4], bg[4];
#pragma unroll
            for (int m = 0; m < 4; m++)
                af[m] = *reinterpret_cast<const bf16x8*>(&As[(wr + m * 16 + l15) * 64 + kk * 32 + lg * 8]);
#pragma unroll
            for (int n = 0; n < 4; n++)
                bg[n] = *reinterpret_cast<const bf16x8*>(&Bs[(wc + n * 16 + l15) * 64 + kk * 32 + lg * 8]);
#pragma unroll
            for (int m = 0; m < 4; m++)
#pragma unroll
                for (int n = 0; n < 4; n++)
                    acc[m][n] = __builtin_amdgcn_mfma_f32_16x16x32_bf16(af[m], bg[n], acc[m][n], 0, 0, 0);
        }
        __builtin_amdgcn_s_setprio(0);
    }

#pragma unroll
    for (int m = 0; m < 4; m++)
#pragma unroll
        for (int n = 0; n < 4; n++)
#pragma unroll
            for (int r = 0; r < 4; r++) {
                int row = row0 + wr + m * 16 + lg * 4 + r;
                int col = col0 + wc + n * 16 + l15;
                C[(size_t)row * N + col] = acc[m][n][r];
            }
}

// ---------------------------------------------------------------- RoPE + L2 norm
__global__ __launch_bounds__(256) void rope_norm_q(const float* __restrict__ qkvf,
                                                   const float* __restrict__ cosb,
                                                   const float* __restrict__ sinb,
                                                   const float* __restrict__ sqkw,
                                                   u16* __restrict__ qb) {
    int w = blockIdx.x * 4 + (threadIdx.x >> 6);
    int lane = threadIdx.x & 63;
    int h = w & (NH - 1), s = w >> 4;
    const float* src = qkvf + (size_t)s * 4096 + h * 128;
    float x0 = src[lane], x1 = src[lane + 64];
    float c0 = cosb[s * 128 + lane], c1 = cosb[s * 128 + 64 + lane];
    float s0 = sinb[s * 128 + lane], s1 = sinb[s * 128 + 64 + lane];
    float y0 = x0 * c0 - x1 * s0;
    float y1 = x1 * c1 + x0 * s1;
    float ss = y0 * y0 + y1 * y1;
#pragma unroll
    for (int off = 32; off; off >>= 1) ss += __shfl_xor(ss, off);
    float inv = 1.f / (sqrtf(ss) + 1e-8f);
    float w0 = sqkw[h * 128 + lane] * 50.f;
    float w1 = sqkw[h * 128 + 64 + lane] * 50.f;
    y0 *= inv * w0 * w0;
    y1 *= inv * w1 * w1;
    u16* dst = qb + ((size_t)h * S_LEN + s) * 128;
    dst[lane] = f2b(y0);
    dst[lane + 64] = f2b(y1);
}

__global__ __launch_bounds__(256) void rope_norm_k(const float* __restrict__ qkvf,
                                                   const float* __restrict__ cosb,
                                                   const float* __restrict__ sinb,
                                                   u16* __restrict__ kb) {
    int w = blockIdx.x * 4 + (threadIdx.x >> 6);
    int lane = threadIdx.x & 63;
    int g = w & (NKV - 1), s = w >> 3;
    const float* src = qkvf + (size_t)s * 4096 + 2048 + g * 128;
    float x0 = src[lane], x1 = src[lane + 64];
    float c0 = cosb[s * 128 + lane], c1 = cosb[s * 128 + 64 + lane];
    float s0 = sinb[s * 128 + lane], s1 = sinb[s * 128 + 64 + lane];
    float y0 = x0 * c0 - x1 * s0;
    float y1 = x1 * c1 + x0 * s1;
    float ss = y0 * y0 + y1 * y1;
#pragma unroll
    for (int off = 32; off; off >>= 1) ss += __shfl_xor(ss, off);
    float inv = 1.f / (sqrtf(ss) + 1e-8f);
    u16* dst = kb + ((size_t)g * S_LEN + s) * 128;
    dst[lane] = f2b(y0 * inv);
    dst[lane + 64] = f2b(y1 * inv);
}

// ---------------------------------------------------------------- MFMA flash attention
// 64 q-rows/block, 4 waves x 16 rows. K-tiles of 64.
// Ks [64][128] / Vs [128][64]: LINEAR global_load_lds dest with inverse-swizzled
// per-lane global source; reads apply byte ^= (row&7)<<4 (rule-21 pair).
// Q frags loaded once from global. Pb re-layouts P for PV A-frags.
__global__ __launch_bounds__(256) void attn_mfma(const u16* __restrict__ Qb,  // [16][S][128]
                                                 const u16* __restrict__ Kb,  // [8][S][128]
                                                 const u16* __restrict__ Vt,  // [1024][S]
                                                 u16* __restrict__ Ao) {      // [S][2048]
    __shared__ alignas(16) u16 Ks[64 * 128];
    __shared__ alignas(16) u16 Vs[128 * 64];
    __shared__ alignas(16) u16 Pb[4][16][72];

    int tid = threadIdx.x, lane = tid & 63, wv = tid >> 6;
    int h = blockIdx.x & (NH - 1);
    int z = blockIdx.x >> 4;
    int qi = (z < 16) ? (31 - z) : (z - 16);   // pair big+small on a CU (sum=33 tiles)
    int qb0 = qi * 64;
    int g = h >> 1;
    int l15 = lane & 15, lg = lane >> 4;

    // Q fragments straight from global (one-time, L2-resident)
    bf16x8 qf[4];
    {
        const u16* qrow = Qb + ((size_t)h * S_LEN + qb0 + wv * 16 + l15) * 128;
#pragma unroll
        for (int kd = 0; kd < 4; kd++)
            qf[kd] = *reinterpret_cast<const bf16x8*>(qrow + kd * 32 + lg * 8);
    }

    const u16* kbase = Kb + (size_t)g * S_LEN * 128;
    const u16* vbase = Vt + (size_t)g * 128 * S_LEN;

    float m[4], l[4];
    f32x4 oacc[8];
#pragma unroll
    for (int r = 0; r < 4; r++) { m[r] = -1e30f; l[r] = 0.f; }
#pragma unroll
    for (int dt = 0; dt < 8; dt++) oacc[dt] = (f32x4){0.f, 0.f, 0.f, 0.f};

    int nt = qi + 1;
    for (int t = 0; t < nt; ++t) {
        int k0 = t * 64;
        __syncthreads();   // previous tile fully consumed
        // stage K [64 rows][128B-swizzle]: linear dest, inverse-swizzled source
#pragma unroll
        for (int i = 0; i < 4; i++) {
            int slot = i * 4 + wv;                 // 0..15, wave-uniform
            int rk = slot * 4 + lg;                // K row 0..63
            int ck = l15 ^ (rk & 7);               // source 16B chunk 0..15
            __builtin_amdgcn_global_load_lds(AS1(kbase + (size_t)(k0 + rk) * 128 + ck * 8),
                                             AS3(Ks + slot * 512), 16, 0, 0);
            int rv = slot * 8 + (lane >> 3);       // V row 0..127
            int cv = (lane & 7) ^ (rv & 7);        // source chunk 0..7
            __builtin_amdgcn_global_load_lds(AS1(vbase + (size_t)rv * S_LEN + k0 + cv * 8),
                                             AS3(Vs + slot * 512), 16, 0, 0);
        }
        __syncthreads();   // vmcnt drained -> tiles ready

        // S = Q K^T
        f32x4 sacc[4];
#pragma unroll
        for (int kt = 0; kt < 4; kt++) sacc[kt] = (f32x4){0.f, 0.f, 0.f, 0.f};
        __builtin_amdgcn_s_setprio(1);
#pragma unroll
        for (int kt = 0; kt < 4; kt++) {
            int r = kt * 16 + l15;
#pragma unroll
            for (int kd = 0; kd < 4; kd++) {
                int col = kd * 64 + lg * 16;       // byte offset in row
                bf16x8 kf = *reinterpret_cast<const bf16x8*>((char*)Ks + r * 256 + (col ^ ((r & 7) << 4)));
                sacc[kt] = __builtin_amdgcn_mfma_f32_16x16x32_bf16(qf[kd], kf, sacc[kt], 0, 0, 0);
            }
        }
        __builtin_amdgcn_s_setprio(0);

        bool maskt = (t == nt - 1);
#pragma unroll
        for (int kt = 0; kt < 4; kt++)
#pragma unroll
            for (int r = 0; r < 4; r++) {
                float s = sacc[kt][r] * SCALE_QK;
                if (maskt) {
                    int key = k0 + kt * 16 + l15;
                    int q = qb0 + wv * 16 + lg * 4 + r;
                    if (key > q) s = -1e30f;
                }
                sacc[kt][r] = s;
            }

        // online softmax (rows across 16-lane groups)
        float pnew[4][4];
        float scl[4];
#pragma unroll
        for (int r = 0; r < 4; r++) {
            float tm = fmaxf(fmaxf(sacc[0][r], sacc[1][r]), fmaxf(sacc[2][r], sacc[3][r]));
            tm = fmaxf(tm, __shfl_xor(tm, 1));
            tm = fmaxf(tm, __shfl_xor(tm, 2));
            tm = fmaxf(tm, __shfl_xor(tm, 4));
            tm = fmaxf(tm, __shfl_xor(tm, 8));
            float mn = fmaxf(m[r], tm);
            scl[r] = __expf(m[r] - mn);
            m[r] = mn;
            float ls = 0.f;
#pragma unroll
            for (int kt = 0; kt < 4; kt++) {
                float p = __expf(sacc[kt][r] - mn);
                pnew[kt][r] = p;
                ls += p;
            }
            ls += __shfl_xor(ls, 1);
            ls += __shfl_xor(ls, 2);
            ls += __shfl_xor(ls, 4);
            ls += __shfl_xor(ls, 8);
            l[r] = l[r] * scl[r] + ls;
        }

#pragma unroll
        for (int dt = 0; dt < 8; dt++)
#pragma unroll
            for (int r = 0; r < 4; r++) oacc[dt][r] *= scl[r];

        // P -> wave-private LDS (re-layout for PV A-frags)
#pragma unroll
        for (int kt = 0; kt < 4; kt++)
#pragma unroll
            for (int r = 0; r < 4; r++)
                Pb[wv][lg * 4 + r][kt * 16 + l15] = f2b(pnew[kt][r]);

        // O += P V
        __builtin_amdgcn_s_setprio(1);
#pragma unroll
        for (int ks = 0; ks < 2; ks++) {
            bf16x8 pf = *reinterpret_cast<const bf16x8*>(&Pb[wv][l15][ks * 32 + lg * 8]);
#pragma unroll
            for (int dt = 0; dt < 8; dt++) {
                int r = dt * 16 + l15;
                int col = ks * 64 + lg * 16;
                bf16x8 vf = *reinterpret_cast<const bf16x8*>((char*)Vs + r * 128 + (col ^ ((r & 7) << 4)));
                oacc[dt] = __builtin_amdgcn_mfma_f32_16x16x32_bf16(pf, vf, oacc[dt], 0, 0, 0);
            }
        }
        __builtin_amdgcn_s_setprio(0);
    }

    float inv[4];
#pragma unroll
    for (int r = 0; r < 4; r++) inv[r] = 1.f / l[r];
#pragma unroll
    for (int dt = 0; dt < 8; dt++)
#pragma unroll
        for (int r = 0; r < 4; r++) {
            int q = qb0 + wv * 16 + lg * 4 + r;
            Ao[(size_t)q * 2048 + h * 128 + dt * 16 + l15] = f2b(oacc[dt][r] * inv[r]);
        }
}

// ---------------------------------------------------------------- launch
extern "C" void kernel_launch(void* const* d_in, const int* in_sizes, int n_in,
                              void* d_out, int out_size, void* d_ws, size_t ws_size,
                              hipStream_t stream) {
    const float* hs   = (const float*)d_in[0];
    const float* cosb = (const float*)d_in[1];
    const float* sinb = (const float*)d_in[2];
    // d_in[3] attention_mask: pure causal, implemented analytically
    const float* Wq   = (const float*)d_in[4];
    const float* Wk   = (const float*)d_in[5];
    const float* Wv   = (const float*)d_in[6];
    const float* Wo   = (const float*)d_in[7];
    const float* sqkw = (const float*)d_in[8];

    char* ws = (char*)d_ws;
    u16*   hsb  = (u16*)(ws);                       //  8.4 MB
    u16*   wcat = (u16*)(ws + 8388608);             // 16.8 MB (Wq;Wk;Wv)
    u16*   wob  = (u16*)(ws + 25165824);            //  8.4 MB
    float* qkvf = (float*)(ws + 33554432);          // 33.6 MB
    u16*   qb   = (u16*)(ws + 67108864);            //  8.4 MB
    u16*   kb   = (u16*)(ws + 75497472);            //  4.2 MB
    u16*   vt   = (u16*)(ws + 79691776);            //  4.2 MB (V^T)
    u16*   ao   = (u16*)(ws + 83886080);            //  8.4 MB

    // fused casts
    cast_all<<<16384, 256, 0, stream>>>(hs, Wq, Wk, Wv, Wo, hsb, wcat, wob);

    // QKV projection: [2048][4096] = hsb * wcat^T
    gemm2<<<dim3(32, 16), 256, 0, stream>>>(hsb, wcat, qkvf, 2048, 4096, 2048);

    // RoPE + norms + V transpose-cast
    rope_norm_q<<<8192, 256, 0, stream>>>(qkvf, cosb, sinb, sqkw, qb);
    rope_norm_k<<<4096, 256, 0, stream>>>(qkvf, cosb, sinb, kb);
    cast_v_t<<<512, 256, 0, stream>>>(qkvf, vt);

    // MFMA flash attention
    attn_mfma<<<512, 256, 0, stream>>>(qb, kb, vt, ao);

    // output projection -> f32 d_out
    gemm2<<<dim3(16, 16), 256, 0, stream>>>(ao, wob, (float*)d_out, 2048, 2048, 2048);
}

// Round 4
// 191.892 us; speedup vs baseline: 3.6524x; 1.0255x over previous
//
#include <hip/hip_runtime.h>

typedef unsigned short u16;
typedef __attribute__((ext_vector_type(4))) float f32x4;
typedef __attribute__((ext_vector_type(8))) __bf16 bf16x8;
typedef __attribute__((ext_vector_type(8))) u16 u16x8;
typedef __attribute__((ext_vector_type(4))) u16 u16x4;

#define S_LEN 2048
#define NH 16
#define NKV 8
#define SCALE_QK 11.313708498984761f  /* sqrt(128) */

#define AS1(p) ((const __attribute__((address_space(1))) void*)(p))
#define AS3(p) ((__attribute__((address_space(3))) void*)(p))

__device__ __forceinline__ float b2f(u16 u) {
    return __uint_as_float(((unsigned int)u) << 16);
}
__device__ __forceinline__ u16 f2b(float f) {
    unsigned int x = __float_as_uint(f);
    unsigned int r = (x + 0x7FFFu + ((x >> 16) & 1u)) >> 16;
    return (u16)r;
}

// ---------------------------------------------------------------- fused casts
__global__ __launch_bounds__(256) void cast_all(const float* __restrict__ hs,
                                                const float* __restrict__ Wq,
                                                const float* __restrict__ Wk,
                                                const float* __restrict__ Wv,
                                                const float* __restrict__ Wo,
                                                u16* __restrict__ hsb,
                                                u16* __restrict__ wcat,
                                                u16* __restrict__ wob) {
    int i = blockIdx.x * 256 + threadIdx.x;   // 0 .. 4194303 quads
    const float* src; u16* dst; int off;
    if (i < 1048576)      { src = hs; dst = hsb;            off = i; }
    else if (i < 2097152) { src = Wq; dst = wcat;           off = i - 1048576; }
    else if (i < 2621440) { src = Wk; dst = wcat + 4194304; off = i - 2097152; }
    else if (i < 3145728) { src = Wv; dst = wcat + 6291456; off = i - 2621440; }
    else                  { src = Wo; dst = wob;            off = i - 3145728; }
    f32x4 v = reinterpret_cast<const f32x4*>(src)[off];
    u16x4 o;
    o[0] = f2b(v[0]); o[1] = f2b(v[1]); o[2] = f2b(v[2]); o[3] = f2b(v[3]);
    reinterpret_cast<u16x4*>(dst)[off] = o;
}

// V slice of QKVf -> vt [gd=g*128+d][s] bf16 (transposed for PV B-frags)
__global__ __launch_bounds__(256) void cast_v_t(const float* __restrict__ qkvf,
                                                u16* __restrict__ vt) {
    __shared__ float tile[64][65];
    int s0 = (blockIdx.x & 31) * 64;
    int c0 = (blockIdx.x >> 5) * 64;
    for (int i = threadIdx.x; i < 64 * 64; i += 256) {
        int r = i >> 6, c = i & 63;
        tile[r][c] = qkvf[(size_t)(s0 + r) * 4096 + 3072 + c0 + c];
    }
    __syncthreads();
    for (int i = threadIdx.x; i < 64 * 64; i += 256) {
        int r = i >> 6, c = i & 63;
        vt[(size_t)(c0 + r) * 2048 + s0 + c] = f2b(tile[c][r]);
    }
}

// ---------------------------------------------------------------- GEMM (dbuf 2-phase)
// C[M][N] = A[M][K] * B[N][K]^T, bf16 in, f32 out. BK=64, double-buffered
// linear LDS + global_load_lds(16B); prefetch issued before compute, one
// __syncthreads per K-step (its vmcnt(0) is the tile-ready drain).
template<int BM, int BN, int WM, int WN>
__global__ __launch_bounds__(256) void gemm_t(const u16* __restrict__ A,
                                              const u16* __restrict__ B,
                                              float* __restrict__ C,
                                              int M, int N, int K) {
    constexpr int MR = BM / WM / 16;
    constexpr int NR = BN / WN / 16;
    __shared__ alignas(16) u16 As[2][BM * 64];
    __shared__ alignas(16) u16 Bs[2][BN * 64];
    int tid = threadIdx.x, lane = tid & 63, wave = tid >> 6;
    int row0 = blockIdx.y * BM, col0 = blockIdx.x * BN;
    int wr = (wave / WN) * (BM / WM);
    int wc = (wave % WN) * (BN / WN);
    int l15 = lane & 15, lg = lane >> 4;

    f32x4 acc[MR][NR] = {};

    auto stage = [&](int bf, int k0) {
#pragma unroll
        for (int i = 0; i < BM / 32; i++) {
            int slot = i * 4 + wave;
            int r = slot * 8 + (lane >> 3);
            int c = lane & 7;
            __builtin_amdgcn_global_load_lds(AS1(A + (size_t)(row0 + r) * K + k0 + c * 8),
                                             AS3(&As[bf][slot * 512]), 16, 0, 0);
        }
#pragma unroll
        for (int i = 0; i < BN / 32; i++) {
            int slot = i * 4 + wave;
            int r = slot * 8 + (lane >> 3);
            int c = lane & 7;
            __builtin_amdgcn_global_load_lds(AS1(B + (size_t)(col0 + r) * K + k0 + c * 8),
                                             AS3(&Bs[bf][slot * 512]), 16, 0, 0);
        }
    };

    stage(0, 0);
    __syncthreads();

    int nk = K >> 6, buf = 0;
    for (int t = 0; t < nk; ++t) {
        if (t + 1 < nk) stage(buf ^ 1, (t + 1) * 64);

        __builtin_amdgcn_s_setprio(1);
#pragma unroll
        for (int kk = 0; kk < 2; kk++) {
            bf16x8 af[MR], bg[NR];
#pragma unroll
            for (int m = 0; m < MR; m++)
                af[m] = *reinterpret_cast<const bf16x8*>(&As[buf][(wr + m * 16 + l15) * 64 + kk * 32 + lg * 8]);
#pragma unroll
            for (int n = 0; n < NR; n++)
                bg[n] = *reinterpret_cast<const bf16x8*>(&Bs[buf][(wc + n * 16 + l15) * 64 + kk * 32 + lg * 8]);
#pragma unroll
            for (int m = 0; m < MR; m++)
#pragma unroll
                for (int n = 0; n < NR; n++)
                    acc[m][n] = __builtin_amdgcn_mfma_f32_16x16x32_bf16(af[m], bg[n], acc[m][n], 0, 0, 0);
        }
        __builtin_amdgcn_s_setprio(0);

        __syncthreads();   // drains vmcnt(0): next tile ready; this tile's reads done
        buf ^= 1;
    }

#pragma unroll
    for (int m = 0; m < MR; m++)
#pragma unroll
        for (int n = 0; n < NR; n++)
#pragma unroll
            for (int r = 0; r < 4; r++) {
                int row = row0 + wr + m * 16 + lg * 4 + r;
                int col = col0 + wc + n * 16 + l15;
                C[(size_t)row * N + col] = acc[m][n][r];
            }
}

// ---------------------------------------------------------------- fused RoPE + L2 norm (Q and K)
__global__ __launch_bounds__(256) void rope_norm(const float* __restrict__ qkvf,
                                                 const float* __restrict__ cosb,
                                                 const float* __restrict__ sinb,
                                                 const float* __restrict__ sqkw,
                                                 u16* __restrict__ qb,
                                                 u16* __restrict__ kb) {
    int w = blockIdx.x * 4 + (threadIdx.x >> 6);   // 0..49151
    int lane = threadIdx.x & 63;
    bool isQ = w < 32768;
    const float* src;
    int s, hg;
    if (isQ) { hg = w & (NH - 1); s = w >> 4; src = qkvf + (size_t)s * 4096 + hg * 128; }
    else     { int w2 = w - 32768; hg = w2 & (NKV - 1); s = w2 >> 3; src = qkvf + (size_t)s * 4096 + 2048 + hg * 128; }
    float x0 = src[lane], x1 = src[lane + 64];
    float c0 = cosb[s * 128 + lane], c1 = cosb[s * 128 + 64 + lane];
    float s0 = sinb[s * 128 + lane], s1 = sinb[s * 128 + 64 + lane];
    float y0 = x0 * c0 - x1 * s0;
    float y1 = x1 * c1 + x0 * s1;
    float ss = y0 * y0 + y1 * y1;
#pragma unroll
    for (int off = 32; off; off >>= 1) ss += __shfl_xor(ss, off);
    float inv = 1.f / (sqrtf(ss) + 1e-8f);
    if (isQ) {
        float w0 = sqkw[hg * 128 + lane] * 50.f;
        float w1 = sqkw[hg * 128 + 64 + lane] * 50.f;
        u16* dst = qb + ((size_t)hg * S_LEN + s) * 128;
        dst[lane]      = f2b(y0 * inv * w0 * w0);
        dst[lane + 64] = f2b(y1 * inv * w1 * w1);
    } else {
        u16* dst = kb + ((size_t)hg * S_LEN + s) * 128;
        dst[lane]      = f2b(y0 * inv);
        dst[lane + 64] = f2b(y1 * inv);
    }
}

// ---------------------------------------------------------------- MFMA flash attention (dbuf 2-phase)
// 64 q-rows/block, 4 waves x 16 rows. K-tiles of 64, double-buffered.
// Ks [64][128] / Vs [128][64]: linear global_load_lds dest, inverse-swizzled
// per-lane source; reads apply byte ^= (row&7)<<4. Q frags in registers.
// T13 defer-max (THR=8). Prefetch-before-compute, one __syncthreads per tile.
__global__ __launch_bounds__(256) void attn_mfma(const u16* __restrict__ Qb,  // [16][S][128]
                                                 const u16* __restrict__ Kb,  // [8][S][128]
                                                 const u16* __restrict__ Vt,  // [1024][S]
                                                 u16* __restrict__ Ao) {      // [S][2048]
    __shared__ alignas(16) u16 Ks[2][64 * 128];
    __shared__ alignas(16) u16 Vs[2][128 * 64];
    __shared__ alignas(16) u16 Pb[4][16][72];

    int tid = threadIdx.x, lane = tid & 63, wv = tid >> 6;
    int h = blockIdx.x & (NH - 1);
    int z = blockIdx.x >> 4;
    int qi = (z < 16) ? (31 - z) : (z - 16);   // pair big+small per CU (sum = 33 tiles)
    int qb0 = qi * 64;
    int g = h >> 1;
    int l15 = lane & 15, lg = lane >> 4;

    // Q fragments straight from global (one-time, L2-resident)
    bf16x8 qf[4];
    {
        const u16* qrow = Qb + ((size_t)h * S_LEN + qb0 + wv * 16 + l15) * 128;
#pragma unroll
        for (int kd = 0; kd < 4; kd++)
            qf[kd] = *reinterpret_cast<const bf16x8*>(qrow + kd * 32 + lg * 8);
    }

    const u16* kbase = Kb + (size_t)g * S_LEN * 128;
    const u16* vbase = Vt + (size_t)g * 128 * S_LEN;

    auto stage = [&](int bf, int k0) {
#pragma unroll
        for (int i = 0; i < 4; i++) {
            int slot = i * 4 + wv;                 // wave-uniform
            int rk = slot * 4 + lg;                // K row 0..63
            int ck = l15 ^ (rk & 7);               // inverse-swizzled source chunk
            __builtin_amdgcn_global_load_lds(AS1(kbase + (size_t)(k0 + rk) * 128 + ck * 8),
                                             AS3(&Ks[bf][slot * 512]), 16, 0, 0);
            int rv = slot * 8 + (lane >> 3);       // V row 0..127
            int cv = (lane & 7) ^ (rv & 7);
            __builtin_amdgcn_global_load_lds(AS1(vbase + (size_t)rv * S_LEN + k0 + cv * 8),
                                             AS3(&Vs[bf][slot * 512]), 16, 0, 0);
        }
    };

    float m[4], l[4];
    f32x4 oacc[8];
#pragma unroll
    for (int r = 0; r < 4; r++) { m[r] = -1e30f; l[r] = 0.f; }
#pragma unroll
    for (int dt = 0; dt < 8; dt++) oacc[dt] = (f32x4){0.f, 0.f, 0.f, 0.f};

    int nt = qi + 1;
    stage(0, 0);
    __syncthreads();

    int buf = 0;
    for (int t = 0; t < nt; ++t) {
        if (t + 1 < nt) stage(buf ^ 1, (t + 1) * 64);   // prefetch overlaps compute
        int k0 = t * 64;

        // S = Q K^T
        f32x4 sacc[4];
#pragma unroll
        for (int kt = 0; kt < 4; kt++) sacc[kt] = (f32x4){0.f, 0.f, 0.f, 0.f};
        __builtin_amdgcn_s_setprio(1);
#pragma unroll
        for (int kt = 0; kt < 4; kt++) {
            int r = kt * 16 + l15;
#pragma unroll
            for (int kd = 0; kd < 4; kd++) {
                int col = kd * 64 + lg * 16;
                bf16x8 kf = *reinterpret_cast<const bf16x8*>((char*)&Ks[buf][0] + r * 256 + (col ^ ((r & 7) << 4)));
                sacc[kt] = __builtin_amdgcn_mfma_f32_16x16x32_bf16(qf[kd], kf, sacc[kt], 0, 0, 0);
            }
        }
        __builtin_amdgcn_s_setprio(0);

        bool maskt = (t == nt - 1);
#pragma unroll
        for (int kt = 0; kt < 4; kt++)
#pragma unroll
            for (int r = 0; r < 4; r++) {
                float s = sacc[kt][r] * SCALE_QK;
                if (maskt) {
                    int key = k0 + kt * 16 + l15;
                    int q = qb0 + wv * 16 + lg * 4 + r;
                    if (key > q) s = -1e30f;
                }
                sacc[kt][r] = s;
            }

        // online softmax with T13 defer-max (THR=8)
        float tmx[4];
        int need = 0;
#pragma unroll
        for (int r = 0; r < 4; r++) {
            float tm = fmaxf(fmaxf(sacc[0][r], sacc[1][r]), fmaxf(sacc[2][r], sacc[3][r]));
            tm = fmaxf(tm, __shfl_xor(tm, 1));
            tm = fmaxf(tm, __shfl_xor(tm, 2));
            tm = fmaxf(tm, __shfl_xor(tm, 4));
            tm = fmaxf(tm, __shfl_xor(tm, 8));
            tmx[r] = tm;
            need |= (tm > m[r] + 8.f) ? 1 : 0;
        }
        float pnew[4][4];
        if (__any(need)) {
#pragma unroll
            for (int r = 0; r < 4; r++) {
                float mn = fmaxf(m[r], tmx[r]);
                float sc = __expf(m[r] - mn);
                m[r] = mn;
                float ls = 0.f;
#pragma unroll
                for (int kt = 0; kt < 4; kt++) {
                    float p = __expf(sacc[kt][r] - mn);
                    pnew[kt][r] = p;
                    ls += p;
                }
                ls += __shfl_xor(ls, 1);
                ls += __shfl_xor(ls, 2);
                ls += __shfl_xor(ls, 4);
                ls += __shfl_xor(ls, 8);
                l[r] = l[r] * sc + ls;
#pragma unroll
                for (int dt = 0; dt < 8; dt++) oacc[dt][r] *= sc;
            }
        } else {
#pragma unroll
            for (int r = 0; r < 4; r++) {
                float ls = 0.f;
#pragma unroll
                for (int kt = 0; kt < 4; kt++) {
                    float p = __expf(sacc[kt][r] - m[r]);   // bounded by e^8
                    pnew[kt][r] = p;
                    ls += p;
                }
                ls += __shfl_xor(ls, 1);
                ls += __shfl_xor(ls, 2);
                ls += __shfl_xor(ls, 4);
                ls += __shfl_xor(ls, 8);
                l[r] += ls;
            }
        }

        // P -> wave-private LDS (re-layout for PV A-frags)
#pragma unroll
        for (int kt = 0; kt < 4; kt++)
#pragma unroll
            for (int r = 0; r < 4; r++)
                Pb[wv][lg * 4 + r][kt * 16 + l15] = f2b(pnew[kt][r]);

        // O += P V
        __builtin_amdgcn_s_setprio(1);
#pragma unroll
        for (int ks = 0; ks < 2; ks++) {
            bf16x8 pf = *reinterpret_cast<const bf16x8*>(&Pb[wv][l15][ks * 32 + lg * 8]);
#pragma unroll
            for (int dt = 0; dt < 8; dt++) {
                int r = dt * 16 + l15;
                int col = ks * 64 + lg * 16;
                bf16x8 vf = *reinterpret_cast<const bf16x8*>((char*)&Vs[buf][0] + r * 128 + (col ^ ((r & 7) << 4)));
                oacc[dt] = __builtin_amdgcn_mfma_f32_16x16x32_bf16(pf, vf, oacc[dt], 0, 0, 0);
            }
        }
        __builtin_amdgcn_s_setprio(0);

        __syncthreads();   // vmcnt(0) drain: next tile staged; this tile's reads done
        buf ^= 1;
    }

    float inv[4];
#pragma unroll
    for (int r = 0; r < 4; r++) inv[r] = 1.f / l[r];
#pragma unroll
    for (int dt = 0; dt < 8; dt++)
#pragma unroll
        for (int r = 0; r < 4; r++) {
            int q = qb0 + wv * 16 + lg * 4 + r;
            Ao[(size_t)q * 2048 + h * 128 + dt * 16 + l15] = f2b(oacc[dt][r] * inv[r]);
        }
}

// ---------------------------------------------------------------- launch
extern "C" void kernel_launch(void* const* d_in, const int* in_sizes, int n_in,
                              void* d_out, int out_size, void* d_ws, size_t ws_size,
                              hipStream_t stream) {
    const float* hs   = (const float*)d_in[0];
    const float* cosb = (const float*)d_in[1];
    const float* sinb = (const float*)d_in[2];
    // d_in[3] attention_mask: pure causal, implemented analytically
    const float* Wq   = (const float*)d_in[4];
    const float* Wk   = (const float*)d_in[5];
    const float* Wv   = (const float*)d_in[6];
    const float* Wo   = (const float*)d_in[7];
    const float* sqkw = (const float*)d_in[8];

    char* ws = (char*)d_ws;
    u16*   hsb  = (u16*)(ws);                       //  8.4 MB
    u16*   wcat = (u16*)(ws + 8388608);             // 16.8 MB (Wq;Wk;Wv)
    u16*   wob  = (u16*)(ws + 25165824);            //  8.4 MB
    float* qkvf = (float*)(ws + 33554432);          // 33.6 MB
    u16*   qb   = (u16*)(ws + 67108864);            //  8.4 MB
    u16*   kb   = (u16*)(ws + 75497472);            //  4.2 MB
    u16*   vt   = (u16*)(ws + 79691776);            //  4.2 MB (V^T)
    u16*   ao   = (u16*)(ws + 83886080);            //  8.4 MB

    // fused casts
    cast_all<<<16384, 256, 0, stream>>>(hs, Wq, Wk, Wv, Wo, hsb, wcat, wob);

    // QKV projection: [2048][4096] = hsb * wcat^T
    gemm_t<128, 128, 2, 2><<<dim3(32, 16), 256, 0, stream>>>(hsb, wcat, qkvf, 2048, 4096, 2048);

    // fused RoPE + norms, then V transpose-cast
    rope_norm<<<12288, 256, 0, stream>>>(qkvf, cosb, sinb, sqkw, qb, kb);
    cast_v_t<<<512, 256, 0, stream>>>(qkvf, vt);

    // MFMA flash attention
    attn_mfma<<<512, 256, 0, stream>>>(qb, kb, vt, ao);

    // output projection -> f32 d_out (128x64 tiles -> 512 blocks, 2/CU)
    gemm_t<128, 64, 4, 1><<<dim3(32, 16), 256, 0, stream>>>(ao, wob, (float*)d_out, 2048, 2048, 2048);
}

// Round 6
// 174.107 us; speedup vs baseline: 4.0255x; 1.1021x over previous
//
#include <hip/hip_runtime.h>

typedef unsigned short u16;
typedef __attribute__((ext_vector_type(4))) float f32x4;
typedef __attribute__((ext_vector_type(8))) __bf16 bf16x8;
typedef __attribute__((ext_vector_type(8))) u16 u16x8;
typedef __attribute__((ext_vector_type(4))) u16 u16x4;

#define S_LEN 2048
#define NH 16
#define NKV 8
// sqrt(128) * log2(e) folded into Q at rope_norm; softmax runs in exp2 space
#define QSCALE_LOG2E 16.322118857f
#define M2INIT 16.6f   /* fixed max: |s2| <= 16.33*(1+bf16 eps) < 16.5 */
#define EXP2(x) __builtin_amdgcn_exp2f(x)

#define AS1(p) ((const __attribute__((address_space(1))) void*)(p))
#define AS3(p) ((__attribute__((address_space(3))) void*)(p))

__device__ __forceinline__ float b2f(u16 u) {
    return __uint_as_float(((unsigned int)u) << 16);
}
__device__ __forceinline__ u16 f2b(float f) {
    unsigned int x = __float_as_uint(f);
    unsigned int r = (x + 0x7FFFu + ((x >> 16) & 1u)) >> 16;
    return (u16)r;
}

// ---------------------------------------------------------------- fused casts
__global__ __launch_bounds__(256) void cast_all(const float* __restrict__ hs,
                                                const float* __restrict__ Wq,
                                                const float* __restrict__ Wk,
                                                const float* __restrict__ Wv,
                                                const float* __restrict__ Wo,
                                                u16* __restrict__ hsb,
                                                u16* __restrict__ wcat,
                                                u16* __restrict__ wob) {
    int i = blockIdx.x * 256 + threadIdx.x;   // 0 .. 4194303 quads
    const float* src; u16* dst; int off;
    if (i < 1048576)      { src = hs; dst = hsb;            off = i; }
    else if (i < 2097152) { src = Wq; dst = wcat;           off = i - 1048576; }
    else if (i < 2621440) { src = Wk; dst = wcat + 4194304; off = i - 2097152; }
    else if (i < 3145728) { src = Wv; dst = wcat + 6291456; off = i - 2621440; }
    else                  { src = Wo; dst = wob;            off = i - 3145728; }
    f32x4 v = reinterpret_cast<const f32x4*>(src)[off];
    u16x4 o;
    o[0] = f2b(v[0]); o[1] = f2b(v[1]); o[2] = f2b(v[2]); o[3] = f2b(v[3]);
    reinterpret_cast<u16x4*>(dst)[off] = o;
}

// V slice of QKVf -> vt [gd=g*128+d][s] bf16 (transposed for PV B-frags)
__global__ __launch_bounds__(256) void cast_v_t(const float* __restrict__ qkvf,
                                                u16* __restrict__ vt) {
    __shared__ float tile[64][65];
    int s0 = (blockIdx.x & 31) * 64;
    int c0 = (blockIdx.x >> 5) * 64;
    for (int i = threadIdx.x; i < 64 * 64; i += 256) {
        int r = i >> 6, c = i & 63;
        tile[r][c] = qkvf[(size_t)(s0 + r) * 4096 + 3072 + c0 + c];
    }
    __syncthreads();
    for (int i = threadIdx.x; i < 64 * 64; i += 256) {
        int r = i >> 6, c = i & 63;
        vt[(size_t)(c0 + r) * 2048 + s0 + c] = f2b(tile[c][r]);
    }
}

// ---------------------------------------------------------------- GEMM (dbuf 2-phase)
template<int BM, int BN, int WM, int WN>
__global__ __launch_bounds__(256) void gemm_t(const u16* __restrict__ A,
                                              const u16* __restrict__ B,
                                              float* __restrict__ C,
                                              int M, int N, int K) {
    constexpr int MR = BM / WM / 16;
    constexpr int NR = BN / WN / 16;
    __shared__ alignas(16) u16 As[2][BM * 64];
    __shared__ alignas(16) u16 Bs[2][BN * 64];
    int tid = threadIdx.x, lane = tid & 63, wave = tid >> 6;
    int row0 = blockIdx.y * BM, col0 = blockIdx.x * BN;
    int wr = (wave / WN) * (BM / WM);
    int wc = (wave % WN) * (BN / WN);
    int l15 = lane & 15, lg = lane >> 4;

    f32x4 acc[MR][NR] = {};

    auto stage = [&](int bf, int k0) {
#pragma unroll
        for (int i = 0; i < BM / 32; i++) {
            int slot = i * 4 + wave;
            int r = slot * 8 + (lane >> 3);
            int c = lane & 7;
            __builtin_amdgcn_global_load_lds(AS1(A + (size_t)(row0 + r) * K + k0 + c * 8),
                                             AS3(&As[bf][slot * 512]), 16, 0, 0);
        }
#pragma unroll
        for (int i = 0; i < BN / 32; i++) {
            int slot = i * 4 + wave;
            int r = slot * 8 + (lane >> 3);
            int c = lane & 7;
            __builtin_amdgcn_global_load_lds(AS1(B + (size_t)(col0 + r) * K + k0 + c * 8),
                                             AS3(&Bs[bf][slot * 512]), 16, 0, 0);
        }
    };

    stage(0, 0);
    __syncthreads();

    int nk = K >> 6, buf = 0;
    for (int t = 0; t < nk; ++t) {
        if (t + 1 < nk) stage(buf ^ 1, (t + 1) * 64);

        __builtin_amdgcn_s_setprio(1);
#pragma unroll
        for (int kk = 0; kk < 2; kk++) {
            bf16x8 af[MR], bg[NR];
#pragma unroll
            for (int m = 0; m < MR; m++)
                af[m] = *reinterpret_cast<const bf16x8*>(&As[buf][(wr + m * 16 + l15) * 64 + kk * 32 + lg * 8]);
#pragma unroll
            for (int n = 0; n < NR; n++)
                bg[n] = *reinterpret_cast<const bf16x8*>(&Bs[buf][(wc + n * 16 + l15) * 64 + kk * 32 + lg * 8]);
#pragma unroll
            for (int m = 0; m < MR; m++)
#pragma unroll
                for (int n = 0; n < NR; n++)
                    acc[m][n] = __builtin_amdgcn_mfma_f32_16x16x32_bf16(af[m], bg[n], acc[m][n], 0, 0, 0);
        }
        __builtin_amdgcn_s_setprio(0);

        __syncthreads();
        buf ^= 1;
    }

#pragma unroll
    for (int m = 0; m < MR; m++)
#pragma unroll
        for (int n = 0; n < NR; n++)
#pragma unroll
            for (int r = 0; r < 4; r++) {
                int row = row0 + wr + m * 16 + lg * 4 + r;
                int col = col0 + wc + n * 16 + l15;
                C[(size_t)row * N + col] = acc[m][n][r];
            }
}

// ---------------------------------------------------------------- fused RoPE + L2 norm (Q and K)
__global__ __launch_bounds__(256) void rope_norm(const float* __restrict__ qkvf,
                                                 const float* __restrict__ cosb,
                                                 const float* __restrict__ sinb,
                                                 const float* __restrict__ sqkw,
                                                 u16* __restrict__ qb,
                                                 u16* __restrict__ kb) {
    int w = blockIdx.x * 4 + (threadIdx.x >> 6);
    int lane = threadIdx.x & 63;
    bool isQ = w < 32768;
    const float* src;
    int s, hg;
    if (isQ) { hg = w & (NH - 1); s = w >> 4; src = qkvf + (size_t)s * 4096 + hg * 128; }
    else     { int w2 = w - 32768; hg = w2 & (NKV - 1); s = w2 >> 3; src = qkvf + (size_t)s * 4096 + 2048 + hg * 128; }
    float x0 = src[lane], x1 = src[lane + 64];
    float c0 = cosb[s * 128 + lane], c1 = cosb[s * 128 + 64 + lane];
    float s0 = sinb[s * 128 + lane], s1 = sinb[s * 128 + 64 + lane];
    float y0 = x0 * c0 - x1 * s0;
    float y1 = x1 * c1 + x0 * s1;
    float ss = y0 * y0 + y1 * y1;
#pragma unroll
    for (int off = 32; off; off >>= 1) ss += __shfl_xor(ss, off);
    float inv = 1.f / (sqrtf(ss) + 1e-8f);
    if (isQ) {
        float w0 = sqkw[hg * 128 + lane] * 50.f;
        float w1 = sqkw[hg * 128 + 64 + lane] * 50.f;
        u16* dst = qb + ((size_t)hg * S_LEN + s) * 128;
        dst[lane]      = f2b(y0 * inv * w0 * w0 * QSCALE_LOG2E);
        dst[lane + 64] = f2b(y1 * inv * w1 * w1 * QSCALE_LOG2E);
    } else {
        u16* dst = kb + ((size_t)hg * S_LEN + s) * 128;
        dst[lane]      = f2b(y0 * inv);
        dst[lane + 64] = f2b(y1 * inv);
    }
}

// ---------------------------------------------------------------- MFMA flash attention
// 64 q-rows/block, 4 waves x 16 rows. K-tiles of 64. Single LDS buffer (41KB
// -> 3 blocks/CU), T14 async-STAGE split: global->reg prefetch overlaps
// compute; ds_write (swizzled) between the two barriers. Softmax in exp2
// space with fixed max (nGPT bound |s2|<16.5), defer-max cold path as guard.
__global__ __launch_bounds__(256) void attn_mfma(const u16* __restrict__ Qb,  // [16][S][128]
                                                 const u16* __restrict__ Kb,  // [8][S][128]
                                                 const u16* __restrict__ Vt,  // [1024][S]
                                                 u16* __restrict__ Ao) {      // [S][2048]
    __shared__ alignas(16) u16 Ks[64 * 128];
    __shared__ alignas(16) u16 Vs[128 * 64];
    __shared__ alignas(16) u16 Pb[4][16][72];

    int tid = threadIdx.x, lane = tid & 63, wv = tid >> 6;
    int h = blockIdx.x & (NH - 1);
    int z = blockIdx.x >> 4;
    int qi = (z < 16) ? (31 - z) : (z - 16);   // pair big+small per CU
    int qb0 = qi * 64;
    int g = h >> 1;
    int l15 = lane & 15, lg = lane >> 4;

    // Q fragments from global (one-time, L2-resident); pre-scaled by sqrt(D)*log2e
    bf16x8 qf[4];
    {
        const u16* qrow = Qb + ((size_t)h * S_LEN + qb0 + wv * 16 + l15) * 128;
#pragma unroll
        for (int kd = 0; kd < 4; kd++)
            qf[kd] = *reinterpret_cast<const bf16x8*>(qrow + kd * 32 + lg * 8);
    }

    const u16* kbase = Kb + (size_t)g * S_LEN * 128;
    const u16* vbase = Vt + (size_t)g * 128 * S_LEN;

    // reg-staging mapping: whole-row coverage per wave-write => conflict-free
    int rk = wv * 16 + (lane >> 4);   // K row (+4*i), chunk ck (16B) of 256B row
    int ck = lane & 15;
    int rv = wv * 32 + (lane >> 3);   // V row (+8*i), chunk cv (16B) of 128B row
    int cv = lane & 7;

    u16x8 kreg[4], vreg[4];

    float m2[4], lpart[4];
    f32x4 oacc[8];
#pragma unroll
    for (int r = 0; r < 4; r++) { m2[r] = M2INIT; lpart[r] = 0.f; }
#pragma unroll
    for (int dt = 0; dt < 8; dt++) oacc[dt] = (f32x4){0.f, 0.f, 0.f, 0.f};

    int nt = qi + 1;

    // prologue: load tile 0 into regs
#pragma unroll
    for (int i = 0; i < 4; i++) {
        kreg[i] = *reinterpret_cast<const u16x8*>(kbase + (size_t)(rk + 4 * i) * 128 + ck * 8);
        vreg[i] = *reinterpret_cast<const u16x8*>(vbase + (size_t)(rv + 8 * i) * S_LEN + cv * 8);
    }

    for (int t = 0; t < nt; ++t) {
        int k0 = t * 64;
        __syncthreads();   // all waves done reading previous tile
        // write staged regs -> LDS (swizzled; waits vmcnt via dataflow)
#pragma unroll
        for (int i = 0; i < 4; i++) {
            int r = rk + 4 * i;
            *reinterpret_cast<u16x8*>((char*)Ks + r * 256 + ((ck * 16) ^ ((r & 7) << 4))) = kreg[i];
            int r2 = rv + 8 * i;
            *reinterpret_cast<u16x8*>((char*)Vs + r2 * 128 + ((cv * 16) ^ ((r2 & 7) << 4))) = vreg[i];
        }
        __syncthreads();   // LDS visible

        // issue next tile's global loads now; they complete under compute
        if (t + 1 < nt) {
            int kn = k0 + 64;
#pragma unroll
            for (int i = 0; i < 4; i++) {
                kreg[i] = *reinterpret_cast<const u16x8*>(kbase + (size_t)(kn + rk + 4 * i) * 128 + ck * 8);
                vreg[i] = *reinterpret_cast<const u16x8*>(vbase + (size_t)(rv + 8 * i) * S_LEN + kn + cv * 8);
            }
        }

        // S2 = (Q*log2e*sqrt(D)) K^T
        f32x4 sacc[4];
#pragma unroll
        for (int kt = 0; kt < 4; kt++) sacc[kt] = (f32x4){0.f, 0.f, 0.f, 0.f};
        __builtin_amdgcn_s_setprio(1);
#pragma unroll
        for (int kt = 0; kt < 4; kt++) {
            int r = kt * 16 + l15;
#pragma unroll
            for (int kd = 0; kd < 4; kd++) {
                int col = kd * 64 + lg * 16;
                bf16x8 kf = *reinterpret_cast<const bf16x8*>((char*)Ks + r * 256 + (col ^ ((r & 7) << 4)));
                sacc[kt] = __builtin_amdgcn_mfma_f32_16x16x32_bf16(qf[kd], kf, sacc[kt], 0, 0, 0);
            }
        }
        __builtin_amdgcn_s_setprio(0);

        // causal mask (diagonal tile only)
        if (t == nt - 1) {
#pragma unroll
            for (int kt = 0; kt < 4; kt++)
#pragma unroll
                for (int r = 0; r < 4; r++) {
                    int key = k0 + kt * 16 + l15;
                    int q = qb0 + wv * 16 + lg * 4 + r;
                    if (key > q) sacc[kt][r] = -1e30f;
                }
        }

        // softmax, exp2 space, fixed max + defer-max guard
        int need = 0;
#pragma unroll
        for (int r = 0; r < 4; r++) {
            float tm = fmaxf(fmaxf(sacc[0][r], sacc[1][r]), fmaxf(sacc[2][r], sacc[3][r]));
            need |= (tm > m2[r] + 11.5f) ? 1 : 0;
        }
        if (__builtin_expect(__any(need), 0)) {
            // cold path: true online-softmax rescale (universal correctness)
#pragma unroll
            for (int r = 0; r < 4; r++) {
                float tm = fmaxf(fmaxf(sacc[0][r], sacc[1][r]), fmaxf(sacc[2][r], sacc[3][r]));
                tm = fmaxf(tm, __shfl_xor(tm, 1));
                tm = fmaxf(tm, __shfl_xor(tm, 2));
                tm = fmaxf(tm, __shfl_xor(tm, 4));
                tm = fmaxf(tm, __shfl_xor(tm, 8));
                float mn = fmaxf(m2[r], tm);
                float sc = EXP2(m2[r] - mn);
                m2[r] = mn;
                lpart[r] *= sc;
#pragma unroll
                for (int dt = 0; dt < 8; dt++) oacc[dt][r] *= sc;
            }
        }
        float pnew[4][4];
#pragma unroll
        for (int r = 0; r < 4; r++) {
            float p0 = EXP2(sacc[0][r] - m2[r]);
            float p1 = EXP2(sacc[1][r] - m2[r]);
            float p2 = EXP2(sacc[2][r] - m2[r]);
            float p3 = EXP2(sacc[3][r] - m2[r]);
            pnew[0][r] = p0; pnew[1][r] = p1; pnew[2][r] = p2; pnew[3][r] = p3;
            lpart[r] += (p0 + p1) + (p2 + p3);
        }

        // P -> wave-private LDS (re-layout for PV A-frags)
#pragma unroll
        for (int kt = 0; kt < 4; kt++)
#pragma unroll
            for (int r = 0; r < 4; r++)
                Pb[wv][lg * 4 + r][kt * 16 + l15] = f2b(pnew[kt][r]);

        // O += P V
        __builtin_amdgcn_s_setprio(1);
#pragma unroll
        for (int ks = 0; ks < 2; ks++) {
            bf16x8 pf = *reinterpret_cast<const bf16x8*>(&Pb[wv][l15][ks * 32 + lg * 8]);
#pragma unroll
            for (int dt = 0; dt < 8; dt++) {
                int r = dt * 16 + l15;
                int col = ks * 64 + lg * 16;
                bf16x8 vf = *reinterpret_cast<const bf16x8*>((char*)Vs + r * 128 + (col ^ ((r & 7) << 4)));
                oacc[dt] = __builtin_amdgcn_mfma_f32_16x16x32_bf16(pf, vf, oacc[dt], 0, 0, 0);
            }
        }
        __builtin_amdgcn_s_setprio(0);
    }

    // epilogue: one-time l reduce across the 16-lane row groups
    float inv[4];
#pragma unroll
    for (int r = 0; r < 4; r++) {
        float ls = lpart[r];
        ls += __shfl_xor(ls, 1);
        ls += __shfl_xor(ls, 2);
        ls += __shfl_xor(ls, 4);
        ls += __shfl_xor(ls, 8);
        inv[r] = 1.f / ls;
    }
#pragma unroll
    for (int dt = 0; dt < 8; dt++)
#pragma unroll
        for (int r = 0; r < 4; r++) {
            int q = qb0 + wv * 16 + lg * 4 + r;
            Ao[(size_t)q * 2048 + h * 128 + dt * 16 + l15] = f2b(oacc[dt][r] * inv[r]);
        }
}

// ---------------------------------------------------------------- launch
extern "C" void kernel_launch(void* const* d_in, const int* in_sizes, int n_in,
                              void* d_out, int out_size, void* d_ws, size_t ws_size,
                              hipStream_t stream) {
    const float* hs   = (const float*)d_in[0];
    const float* cosb = (const float*)d_in[1];
    const float* sinb = (const float*)d_in[2];
    // d_in[3] attention_mask: pure causal, implemented analytically
    const float* Wq   = (const float*)d_in[4];
    const float* Wk   = (const float*)d_in[5];
    const float* Wv   = (const float*)d_in[6];
    const float* Wo   = (const float*)d_in[7];
    const float* sqkw = (const float*)d_in[8];

    char* ws = (char*)d_ws;
    u16*   hsb  = (u16*)(ws);                       //  8.4 MB
    u16*   wcat = (u16*)(ws + 8388608);             // 16.8 MB (Wq;Wk;Wv)
    u16*   wob  = (u16*)(ws + 25165824);            //  8.4 MB
    float* qkvf = (float*)(ws + 33554432);          // 33.6 MB
    u16*   qb   = (u16*)(ws + 67108864);            //  8.4 MB
    u16*   kb   = (u16*)(ws + 75497472);            //  4.2 MB
    u16*   vt   = (u16*)(ws + 79691776);            //  4.2 MB (V^T)
    u16*   ao   = (u16*)(ws + 83886080);            //  8.4 MB

    cast_all<<<16384, 256, 0, stream>>>(hs, Wq, Wk, Wv, Wo, hsb, wcat, wob);

    gemm_t<128, 128, 2, 2><<<dim3(32, 16), 256, 0, stream>>>(hsb, wcat, qkvf, 2048, 4096, 2048);

    rope_norm<<<12288, 256, 0, stream>>>(qkvf, cosb, sinb, sqkw, qb, kb);
    cast_v_t<<<512, 256, 0, stream>>>(qkvf, vt);

    attn_mfma<<<512, 256, 0, stream>>>(qb, kb, vt, ao);

    gemm_t<128, 64, 4, 1><<<dim3(32, 16), 256, 0, stream>>>(ao, wob, (float*)d_out, 2048, 2048, 2048);
}